// Round 3
// baseline (149.010 us; speedup 1.0000x reference)
//
#include <hip/hip_runtime.h>
#include <cfloat>
#include <cstdint>

// Sampler: out[row] = argmax_v( nan_to_num(logits)/max(temp,eps) + gumbel(u) )
//          or argmax_v( nan_to_num(logits) ) when temp <= eps.
// Tie-break: lowest index (numpy argmax semantics) via packed u64 key.
//
// Numerics: nan_to_num -> multiply by per-row reciprocal (1 ulp vs IEEE div)
// -> clamp -> INNER log = precise logf (winner candidates have c within
// ~1e-5 of 1.0 where hw log2 loses relative accuracy) -> OUTER log = fast
// __logf (argument w in [1e-7,23] is well-scaled; abs err in g ~1e-5 << O(1)
// top-2 Gumbel gap).

#define TEMP_EPS 1e-6f

static constexpr int V       = 128256;
static constexpr int V4      = V / 4;            // 32064 float4 per row
static constexpr int SEGS    = 16;
static constexpr int SEG_V4  = V4 / SEGS;        // 2004 float4 per segment
static constexpr int ITERS   = 8;                // 7 full + tail
static constexpr int TAIL    = SEG_V4 - 7 * 256; // 212

__device__ __forceinline__ float nan_to_num_f(float x) {
    if (x != x) return 0.0f;                     // NaN -> 0
    return fminf(fmaxf(x, -FLT_MAX), FLT_MAX);   // +-Inf -> +-FLT_MAX
}

// Monotonic float->uint mapping; key = (mapped_val << 32) | ~index.
// 64-bit max picks: larger value; on equal value, smaller index.
__device__ __forceinline__ unsigned long long pack_key(float v, int idx) {
    unsigned b = __float_as_uint(v);
    unsigned mask = (unsigned)(((int)b >> 31)) | 0x80000000u;
    b ^= mask;
    return ((unsigned long long)b << 32) | (unsigned)(~(unsigned)idx);
}

__device__ __forceinline__ unsigned long long umax64(unsigned long long a,
                                                     unsigned long long b) {
    return a > b ? a : b;
}

__global__ __launch_bounds__(256) void sampler_partial_kernel(
    const float* __restrict__ logits,
    const float* __restrict__ temps,
    const float* __restrict__ u,
    unsigned long long* __restrict__ partials) {
    const int row = blockIdx.y;
    const int seg = blockIdx.x;
    const int tid = threadIdx.x;

    const float temp = temps[row];
    const bool greedy = (temp <= TEMP_EPS);
    const float safe_temp = fmaxf(temp, TEMP_EPS);
    const float inv_temp = 1.0f / safe_temp;   // once per block (wave-uniform)

    const float4* __restrict__ l4 = (const float4*)(logits + (size_t)row * V);
    const float4* __restrict__ u4 = (const float4*)(u + (size_t)row * V);

    const float UC_LO = 1e-10f;
    const float UC_HI = (float)(1.0 - 1e-7);

    const int base = seg * SEG_V4;

    // 7 full strided iterations + tail. Tail threads past TAIL re-read
    // element idx[0]; its candidates are already in the max (harmless dup,
    // keeps everything branchless).
    int idx[ITERS];
#pragma unroll
    for (int k = 0; k < ITERS - 1; ++k) idx[k] = base + k * 256 + tid;
    idx[ITERS - 1] = (tid < TAIL) ? (base + (ITERS - 1) * 256 + tid) : (base + tid);

    unsigned long long key = 0ULL;

    if (greedy) {
        float4 lv[ITERS];
#pragma unroll
        for (int k = 0; k < ITERS; ++k) lv[k] = l4[idx[k]];
#pragma unroll
        for (int k = 0; k < ITERS; ++k) {
            const int e = idx[k] * 4;
            unsigned long long k0 = pack_key(nan_to_num_f(lv[k].x), e + 0);
            unsigned long long k1 = pack_key(nan_to_num_f(lv[k].y), e + 1);
            unsigned long long k2 = pack_key(nan_to_num_f(lv[k].z), e + 2);
            unsigned long long k3 = pack_key(nan_to_num_f(lv[k].w), e + 3);
            key = umax64(key, umax64(umax64(k0, k1), umax64(k2, k3)));
        }
    } else {
        // Hoist ALL loads (16 dwordx4 in flight) before compute.
        float4 lv[ITERS], uv[ITERS];
#pragma unroll
        for (int k = 0; k < ITERS; ++k) lv[k] = l4[idx[k]];
#pragma unroll
        for (int k = 0; k < ITERS; ++k) uv[k] = u4[idx[k]];

#pragma unroll
        for (int k = 0; k < ITERS; ++k) {
            const int e = idx[k] * 4;

            float l0 = nan_to_num_f(lv[k].x) * inv_temp;
            float l1 = nan_to_num_f(lv[k].y) * inv_temp;
            float l2 = nan_to_num_f(lv[k].z) * inv_temp;
            float l3 = nan_to_num_f(lv[k].w) * inv_temp;

            float c0 = fminf(fmaxf(uv[k].x, UC_LO), UC_HI);
            float c1 = fminf(fmaxf(uv[k].y, UC_LO), UC_HI);
            float c2 = fminf(fmaxf(uv[k].z, UC_LO), UC_HI);
            float c3 = fminf(fmaxf(uv[k].w, UC_LO), UC_HI);

            // inner: precise; outer: hw log (well-scaled argument)
            float w0 = -logf(c0);
            float w1 = -logf(c1);
            float w2 = -logf(c2);
            float w3 = -logf(c3);

            float g0 = -__logf(w0);
            float g1 = -__logf(w1);
            float g2 = -__logf(w2);
            float g3 = -__logf(w3);

            unsigned long long k0 = pack_key(l0 + g0, e + 0);
            unsigned long long k1 = pack_key(l1 + g1, e + 1);
            unsigned long long k2 = pack_key(l2 + g2, e + 2);
            unsigned long long k3 = pack_key(l3 + g3, e + 3);
            key = umax64(key, umax64(umax64(k0, k1), umax64(k2, k3)));
        }
    }

    // wave (64-lane) shuffle reduction
    for (int o = 32; o > 0; o >>= 1)
        key = umax64(key, __shfl_down(key, o));

    __shared__ unsigned long long sdata[4];
    if ((tid & 63) == 0) sdata[tid >> 6] = key;
    __syncthreads();

    if (tid == 0) {
        for (int w = 1; w < 4; ++w) key = umax64(key, sdata[w]);
        partials[row * SEGS + seg] = key;
    }
}

__global__ __launch_bounds__(64) void sampler_reduce_kernel(
    const unsigned long long* __restrict__ partials,
    int* __restrict__ out) {
    const int row = blockIdx.x;
    const int t = threadIdx.x;
    unsigned long long key = (t < SEGS) ? partials[row * SEGS + t] : 0ULL;
    for (int o = 32; o > 0; o >>= 1)
        key = umax64(key, __shfl_down(key, o));
    if (t == 0)
        out[row] = (int)(~(unsigned)(key & 0xFFFFFFFFull));
}

extern "C" void kernel_launch(void* const* d_in, const int* in_sizes, int n_in,
                              void* d_out, int out_size, void* d_ws, size_t ws_size,
                              hipStream_t stream) {
    const float* logits = (const float*)d_in[0];
    const float* temps  = (const float*)d_in[1];
    const float* u      = (const float*)d_in[2];
    int* out = (int*)d_out;
    const int B = in_sizes[1];   // 128 rows

    unsigned long long* partials = (unsigned long long*)d_ws;  // B*SEGS*8 = 16 KB

    dim3 grid1(SEGS, B);
    hipLaunchKernelGGL(sampler_partial_kernel, grid1, dim3(256), 0, stream,
                       logits, temps, u, partials);
    hipLaunchKernelGGL(sampler_reduce_kernel, dim3(B), dim3(64), 0, stream,
                       partials, out);
}